// Round 1
// baseline (45.045 us; speedup 1.0000x reference)
//
#include <hip/hip_runtime.h>

#define ACT_D 1024
#define ACT_MAX_STEPS 20
#define ACT_THRESHOLD 0.99f

// One 64-lane wave per (b,s) row. Each lane holds 16 floats of x (4 x float4).
// Dot(x,W) reduced in double across the wave; 20-step scalar ACT recurrence
// run redundantly per-lane in fp32 (matches reference op order); state = c*x
// written from registers (x read exactly once from HBM).
__global__ __launch_bounds__(256) void act_kernel(
    const float* __restrict__ x,
    const float* __restrict__ W,
    const float* __restrict__ bvec,
    float* __restrict__ state_out,
    float* __restrict__ ponder_out,
    int n_rows)
{
    const int wave = threadIdx.x >> 6;          // 4 waves per block
    const int lane = threadIdx.x & 63;
    const int row  = blockIdx.x * 4 + wave;
    if (row >= n_rows) return;

    const float* __restrict__ xr = x + (size_t)row * ACT_D;

    float4 xv[4];
    double acc = 0.0;
    #pragma unroll
    for (int j = 0; j < 4; ++j) {
        const int idx = lane * 4 + j * 256;     // contiguous 1 KiB per load across the wave
        xv[j] = *reinterpret_cast<const float4*>(xr + idx);
        const float4 wv = *reinterpret_cast<const float4*>(W + idx);
        acc += (double)xv[j].x * (double)wv.x
             + (double)xv[j].y * (double)wv.y
             + (double)xv[j].z * (double)wv.z
             + (double)xv[j].w * (double)wv.w;
    }

    // 64-lane butterfly reduction (double via paired 32-bit shuffles)
    #pragma unroll
    for (int off = 32; off >= 1; off >>= 1)
        acc += __shfl_xor(acc, off, 64);

    // p = sigmoid(dot + b), computed in double then rounded (near correctly-rounded fp32)
    const float z = (float)acc + bvec[0];
    const float p = (float)(1.0 / (1.0 + exp(-(double)z)));

    // 20-step ACT scalar recurrence, fp32, same op order as reference
    float hp = 0.0f, rem = 0.0f, nup = 0.0f, c = 0.0f;
    #pragma unroll
    for (int t = 0; t < ACT_MAX_STEPS; ++t) {
        const float still = (hp < 1.0f) ? 1.0f : 0.0f;
        const float nh    = ((hp + p * still) > ACT_THRESHOLD) ? still : 0.0f;
        hp  = hp + p * still;
        rem = rem + nh * (1.0f - hp);
        hp  = hp + nh * rem;
        const float uw = p * still + nh * rem;
        c   = (1.0f - uw) * c + uw;
        nup = nup + still;
    }
    const float ponder = nup + rem;

    // state = c * x, written from registers
    float* __restrict__ so = state_out + (size_t)row * ACT_D;
    #pragma unroll
    for (int j = 0; j < 4; ++j) {
        const int idx = lane * 4 + j * 256;
        float4 o;
        o.x = c * xv[j].x;
        o.y = c * xv[j].y;
        o.z = c * xv[j].z;
        o.w = c * xv[j].w;
        *reinterpret_cast<float4*>(so + idx) = o;
    }
    if (lane == 0) ponder_out[row] = ponder;
}

extern "C" void kernel_launch(void* const* d_in, const int* in_sizes, int n_in,
                              void* d_out, int out_size, void* d_ws, size_t ws_size,
                              hipStream_t stream)
{
    const float* x = (const float*)d_in[0];   // (B,S,D) = (8,4096,1024) fp32
    const float* W = (const float*)d_in[1];   // (D,1)
    const float* b = (const float*)d_in[2];   // (1,)

    const int n_rows = in_sizes[0] / ACT_D;   // B*S = 32768

    float* state_out  = (float*)d_out;                      // n_rows * D
    float* ponder_out = (float*)d_out + (size_t)n_rows * ACT_D;  // n_rows

    const int rows_per_block = 4;             // 4 waves of 64
    const int grid = (n_rows + rows_per_block - 1) / rows_per_block;
    act_kernel<<<grid, 256, 0, stream>>>(x, W, b, state_out, ponder_out, n_rows);
}